// Round 7
// baseline (480.789 us; speedup 1.0000x reference)
//
#include <hip/hip_runtime.h>
#include <cstdint>
#include <cstddef>
#include <math.h>

#define NN 100000
#define NE 1600000
#define NB ((NN + 255) / 256)   // 391 node buckets (256 nodes each)
#define EB 400                  // build blocks
#define EPB (NE / EB)           // 4000 edges per block
#define CAP 5120                // padded bucket capacity (mean 4092, sigma~64)

// GEMM tiling: 512 threads, 128 nodes/block, per-thread 4 nodes x 4 feats.
#define GT_NODES 128
#define GT_KC 32
#define GT_STRIDE 132

typedef unsigned short u16;

__device__ __forceinline__ float bf2f(u16 u) {
    union { unsigned i; float f; } c; c.i = ((unsigned)u) << 16; return c.f;
}
__device__ __forceinline__ u16 f2bf(float f) {  // round-to-nearest-even
    union { float f; unsigned int i; } c; c.f = f;
    unsigned int lsb = (c.i >> 16) & 1u;
    return (u16)((c.i + 0x7fffu + lsb) >> 16);
}
__device__ __forceinline__ unsigned int pack2(float a, float b) {
    return (unsigned int)f2bf(a) | ((unsigned int)f2bf(b) << 16);
}

__device__ __forceinline__ int load_idx(const void* ei, int isI64, int pos) {
    if (isI64) return (int)((const long long*)ei)[pos];
    return ((const int*)ei)[pos];
}

// ---------- fused CSR phase A: detect + hist + scatter into padded buckets ----
__global__ __launch_bounds__(256) void k_build(const void* __restrict__ ei,
                                               int* __restrict__ cursor,
                                               int* __restrict__ csr_tmp) {
    __shared__ int sbuf[EPB];      // 16,000 B
    __shared__ int dbuf[EPB];      // 16,000 B
    __shared__ int cnt[NB];
    __shared__ int basel[NB];
    __shared__ int anynz;

    // per-block int64/int32 detection (odd words of first 1024 entries)
    const int* p = (const int*)ei;
    if (threadIdx.x == 0) anynz = 0;
    for (int i = threadIdx.x; i < NB; i += 256) cnt[i] = 0;
    __syncthreads();
    int nz = 0;
    for (int i = threadIdx.x; i < 1024; i += 256) nz |= (p[2 * i + 1] != 0);
    if (nz) anynz = 1;   // benign race: all writers store 1
    __syncthreads();
    int isI64 = (anynz == 0);

    int base = blockIdx.x * EPB;
    for (int i = threadIdx.x; i < EPB; i += 256) {
        int s = load_idx(ei, isI64, base + i);
        int d = load_idx(ei, isI64, NE + base + i);
        sbuf[i] = s;
        dbuf[i] = d;
        atomicAdd(&cnt[d >> 8], 1);
    }
    __syncthreads();
    for (int j = threadIdx.x; j < NB; j += 256) {
        int c = cnt[j];
        int g = c ? atomicAdd(&cursor[j], c) : 0;
        basel[j] = j * CAP + g;
        cnt[j] = 0;   // reuse as local placement cursor
    }
    __syncthreads();
    for (int i = threadIdx.x; i < EPB; i += 256) {
        int s = sbuf[i];
        int d = dbuf[i];
        int bkt = d >> 8;
        int slot = basel[bkt] + atomicAdd(&cnt[bkt], 1);
        csr_tmp[slot] = ((d & 255) << 17) | s;   // dstlocal<<17 | src
    }
}

// ---------- CSR phase B: per-bucket counting sort -> csr + deg/offs/dis ------
__global__ __launch_bounds__(256) void k_sort(const int* __restrict__ cursor,
                                              const int* __restrict__ csr_tmp,
                                              int* __restrict__ csr,
                                              int* __restrict__ deg,
                                              int* __restrict__ offs,
                                              float* __restrict__ dis) {
    __shared__ int h[256];
    __shared__ int sc[256];
    __shared__ int cur[256];
    int j = blockIdx.x;
    int s0 = j * CAP, s1 = s0 + cursor[j];
    h[threadIdx.x] = 0;
    __syncthreads();
    for (int p = s0 + threadIdx.x; p < s1; p += 256)
        atomicAdd(&h[csr_tmp[p] >> 17], 1);
    __syncthreads();
    int v = h[threadIdx.x];
    sc[threadIdx.x] = v;
    __syncthreads();
#pragma unroll
    for (int off = 1; off < 256; off <<= 1) {
        int u = (threadIdx.x >= off) ? sc[threadIdx.x - off] : 0;
        __syncthreads();
        sc[threadIdx.x] += u;
        __syncthreads();
    }
    int excl = sc[threadIdx.x] - v;
    int node = j * 256 + threadIdx.x;
    if (node < NN) {
        deg[node] = v;
        offs[node] = s0 + excl;
        dis[node] = rsqrtf((float)(v + 1));  // +1 self-loop
    }
    cur[threadIdx.x] = excl;
    __syncthreads();
    for (int p = s0 + threadIdx.x; p < s1; p += 256) {
        int pk = csr_tmp[p];
        int dl = pk >> 17;
        int pos = s0 + atomicAdd(&cur[dl], 1);
        csr[pos] = pk & 0x1FFFF;   // plain src index
    }
}

// ---------- register-tiled GEMM (512 thr, 128 nodes/blk, 4x4/thread) ----------
// SIN: input is slice-blocked fp32 [4][NN][16] (valid for K=64 only).
// SOUT: output is slice-blocked bf16 [4][NN][16] (valid for FR=64 only).
template <int K, int FR, bool RELU, bool SIN, bool SOUT>
__global__ __launch_bounds__(512) void k_gemm(const float* __restrict__ x,
                                              const float* __restrict__ W,
                                              const float* __restrict__ dis,
                                              u16* __restrict__ out) {
    __shared__ float xT[GT_KC * GT_STRIDE];   // 16,896 B
    __shared__ float Wc[GT_KC * 64];          //  8,192 B
    const int tid = threadIdx.x;
    const int r = tid >> 4;
    const int c = tid & 15;
    const int f4 = tid & 7;
    const int nrow = tid >> 3;
    const int nbase = blockIdx.x * GT_NODES;

    float acc[4][4];
#pragma unroll
    for (int i = 0; i < 4; ++i)
#pragma unroll
        for (int j = 0; j < 4; ++j) acc[i][j] = 0.f;

    for (int kc = 0; kc < K; kc += GT_KC) {
#pragma unroll
        for (int q = 0; q < 4; ++q) {
            int e = q * 512 + tid;
            int kk = e >> 6, j = e & 63;
            Wc[kk * 64 + j] = (j < FR) ? W[(size_t)(kc + kk) * FR + j] : 0.f;
        }
#pragma unroll
        for (int q = 0; q < 2; ++q) {
            int nl = q * 64 + nrow;
            int n = nbase + nl;
            float4 v = make_float4(0.f, 0.f, 0.f, 0.f);
            if (n < NN) {
                if (SIN) {
                    int k = kc + f4 * 4;
                    v = *(const float4*)(x + (size_t)(k >> 4) * (NN * 16)
                                           + (size_t)n * 16 + (k & 15));
                } else {
                    v = *(const float4*)(x + (size_t)n * K + kc + f4 * 4);
                }
            }
            if (RELU) {
                v.x = fmaxf(v.x, 0.f); v.y = fmaxf(v.y, 0.f);
                v.z = fmaxf(v.z, 0.f); v.w = fmaxf(v.w, 0.f);
            }
            xT[(f4 * 4 + 0) * GT_STRIDE + nl] = v.x;
            xT[(f4 * 4 + 1) * GT_STRIDE + nl] = v.y;
            xT[(f4 * 4 + 2) * GT_STRIDE + nl] = v.z;
            xT[(f4 * 4 + 3) * GT_STRIDE + nl] = v.w;
        }
        __syncthreads();
#pragma unroll 8
        for (int kk = 0; kk < GT_KC; ++kk) {
            float4 a = *(const float4*)&xT[kk * GT_STRIDE + r * 4];
            float4 w = *(const float4*)&Wc[kk * 64 + c * 4];
            float xa[4] = {a.x, a.y, a.z, a.w};
            float wb[4] = {w.x, w.y, w.z, w.w};
#pragma unroll
            for (int i = 0; i < 4; ++i)
#pragma unroll
                for (int j = 0; j < 4; ++j)
                    acc[i][j] = fmaf(xa[i], wb[j], acc[i][j]);
        }
        __syncthreads();
    }
    if (c * 4 < FR) {
#pragma unroll
        for (int i = 0; i < 4; ++i) {
            int n = nbase + r * 4 + i;
            if (n < NN) {
                float dv = dis[n];
                uint2 o;
                o.x = pack2(dv * acc[i][0], dv * acc[i][1]);
                o.y = pack2(dv * acc[i][2], dv * acc[i][3]);
                if (SOUT) {
                    int j0 = c * 4;
                    u16* bp = out + (size_t)(j0 >> 4) * (NN * 16)
                                  + (size_t)n * 16 + (j0 & 15);
                    *(uint2*)bp = o;
                } else {
                    *(uint2*)(out + (size_t)n * FR + c * 4) = o;
                }
            }
        }
    }
}

// ---------- R16: slice gather (16-feat slices, XCD-L2-resident) ----------
// gin_s: [4][NN][16] bf16 (slice = 3.2 MB < 4 MB per-XCD L2).
// slice = blockIdx&3 -> with blockIdx%8->XCD round-robin, XCD k always
// processes slice k&3: random src reads become L2-resident (reuse ~16x).
// 1 node per wave (R14 lesson: keep >=100K wave streams); lane = feat(16)
// x esub(4 parallel edges). Indices staged once (csr[start+lane]), per-edge
// delivery via __shfl (ds_bpermute). Output act_s [4][NN][16] fp32, raw
// v = dis*acc + b (ReLU applied by the consuming GEMM, as in R13).
__global__ __launch_bounds__(256) void k_gath16(const int* __restrict__ offs,
                                                const int* __restrict__ deg,
                                                const int* __restrict__ csr,
                                                const float* __restrict__ dis,
                                                const u16* __restrict__ gin_s,
                                                const float* __restrict__ b,
                                                float* __restrict__ act_s) {
    const int bid = blockIdx.x;
    const int slice = bid & 3;
    const int n = (bid >> 2) * 4 + (threadIdx.x >> 6);   // grid exact: n < NN
    const unsigned lane = threadIdx.x & 63;
    const unsigned feat = lane & 15;
    const unsigned esub = lane >> 4;
    const u16* __restrict__ gs = gin_s + (size_t)slice * (NN * 16);

    int start = __builtin_amdgcn_readfirstlane(offs[n]);
    int len   = __builtin_amdgcn_readfirstlane(deg[n]);

    // self-loop only once (esub 0), others contribute 0
    float acc = (esub == 0) ? bf2f(gs[(unsigned)n * 16 + feat]) : 0.f;

    int myidx = 0;
    if ((int)lane < len) myidx = csr[start + (int)lane];
    int lim = (len < 64) ? len : 64;

    for (int i = 0; i < lim; i += 16) {       // wave-uniform trip count
        int e0 = i + (int)esub;
        int s0 = __shfl(myidx, e0);
        int s1 = __shfl(myidx, e0 + 4);
        int s2 = __shfl(myidx, e0 + 8);
        int s3 = __shfl(myidx, e0 + 12);
        u16 h0 = gs[(unsigned)s0 * 16 + feat];
        u16 h1 = gs[(unsigned)s1 * 16 + feat];
        u16 h2 = gs[(unsigned)s2 * 16 + feat];
        u16 h3 = gs[(unsigned)s3 * 16 + feat];
        float v0 = (e0      < lim) ? bf2f(h0) : 0.f;
        float v1 = (e0 + 4  < lim) ? bf2f(h1) : 0.f;
        float v2 = (e0 + 8  < lim) ? bf2f(h2) : 0.f;
        float v3 = (e0 + 12 < lim) ? bf2f(h3) : 0.f;
        acc += (v0 + v1) + (v2 + v3);
    }
    // rare fallback: deg > 64 (each esub group handles every 4th edge)
    if (len > 64) {
        for (int i = 64 + (int)esub; i < len; i += 4) {
            int s = csr[start + i];
            acc += bf2f(gs[(unsigned)s * 16 + feat]);
        }
    }
    // reduce across the 4 esub groups (lanes differing in bits 4,5)
    acc += __shfl_xor(acc, 16);
    acc += __shfl_xor(acc, 32);

    float v = dis[n] * acc + b[slice * 16 + feat];
    if (esub == 0)
        act_s[(size_t)slice * (NN * 16) + (unsigned)n * 16 + feat] = v;
}

// ---------- gather batch helper: B edges, SGPR row-base addressing ----------
template <int F, int B, bool MASK>
__device__ __forceinline__ float gb(int myidx, int i, int lim,
                                    const u16* __restrict__ g, unsigned fc) {
    const u16* rp[B];
#pragma unroll
    for (int k = 0; k < B; ++k) {
        int s = __builtin_amdgcn_readlane(myidx, i + k);
        rp[k] = g + (size_t)(unsigned)s * (unsigned)F;   // uniform -> SGPR base
    }
    u16 hh[B];
#pragma unroll
    for (int k = 0; k < B; ++k) hh[k] = rp[k][fc];
    float t0 = 0.f, t1 = 0.f, t2 = 0.f, t3 = 0.f;
#pragma unroll
    for (int k = 0; k < B; ++k) {
        float v = bf2f(hh[k]);
        if (MASK) v = (i + k < lim) ? v : 0.f;
        if ((k & 3) == 0) t0 += v;
        else if ((k & 3) == 1) t1 += v;
        else if ((k & 3) == 2) t2 += v;
        else t3 += v;
    }
    return (t0 + t1) + (t2 + t3);
}

// per-node row aggregation (R13 proven form), F = source row width
template <int F>
__device__ __forceinline__ float grow(int n, unsigned fc,
                                      const int* __restrict__ offs,
                                      const int* __restrict__ deg,
                                      const int* __restrict__ csr,
                                      const u16* __restrict__ g) {
    int start = __builtin_amdgcn_readfirstlane(offs[n]);
    int len   = __builtin_amdgcn_readfirstlane(deg[n]);
    float acc = bf2f(g[(unsigned)n * F + fc]);  // self-loop (pre-scaled)

    int myidx = 0;
    if ((int)fc < len) myidx = csr[start + (int)fc];
    int lim = (len < 64) ? len : 64;

    if (lim > 0) {
        if (lim >= 33) {
            int i = 0;
            for (; i + 16 <= lim; i += 16)
                acc += gb<F, 16, false>(myidx, i, lim, g, fc);
            if (i < lim)
                acc += gb<F, 16, true>(myidx, i, lim, g, fc);
        } else if (lim >= 17) {
            acc += gb<F, 32, true>(myidx, 0, lim, g, fc);
        } else if (lim == 16) {
            acc += gb<F, 16, false>(myidx, 0, lim, g, fc);
        } else {
            acc += gb<F, 16, true>(myidx, 0, lim, g, fc);
        }
    }
    // rare fallback: deg > 64
    if (len > 64) {
        int ii = 64;
        for (; ii + 2 <= len; ii += 2) {
            int s0 = __builtin_amdgcn_readfirstlane(csr[start + ii + 0]);
            int s1 = __builtin_amdgcn_readfirstlane(csr[start + ii + 1]);
            u16 h0 = g[(unsigned)s0 * F + fc];
            u16 h1 = g[(unsigned)s1 * F + fc];
            acc += bf2f(h0) + bf2f(h1);
        }
        if (ii < len) {
            int s0 = __builtin_amdgcn_readfirstlane(csr[start + ii]);
            acc += bf2f(g[(unsigned)s0 * F + fc]);
        }
    }
    return acc;
}

// ---------- final gather (layer-3 aggregation + bias + log_softmax) ----------
template <int F, bool SOFTMAX>
__global__ __launch_bounds__(256) void k_gather(const int* __restrict__ offs,
                                                const int* __restrict__ deg,
                                                const int* __restrict__ csr,
                                                const float* __restrict__ dis,
                                                const u16* __restrict__ g,
                                                const float* __restrict__ b,
                                                float* __restrict__ out) {
    int n = blockIdx.x * 4 + (threadIdx.x >> 6);
    unsigned f = threadIdx.x & 63;
    if (n >= NN) return;
    unsigned fc = (f < (unsigned)F) ? f : 0u;
    float dvn = dis[n];
    float bf  = b[fc];
    float acc = grow<F>(n, fc, offs, deg, csr, g);
    float v = dvn * acc + bf;
    if (!SOFTMAX) {
        if (f < (unsigned)F) out[(size_t)n * F + f] = v;
    } else {
        float vv = (f < (unsigned)F) ? v : -INFINITY;
        float m = vv;
#pragma unroll
        for (int off = 32; off; off >>= 1) m = fmaxf(m, __shfl_xor(m, off));
        float ex = (f < (unsigned)F) ? __expf(vv - m) : 0.f;
        float sum = ex;
#pragma unroll
        for (int off = 32; off; off >>= 1) sum += __shfl_xor(sum, off);
        if (f < (unsigned)F) out[(size_t)n * F + f] = vv - m - logf(sum);
    }
}

extern "C" void kernel_launch(void* const* d_in, const int* in_sizes, int n_in,
                              void* d_out, int out_size, void* d_ws, size_t ws_size,
                              hipStream_t stream) {
    const float* x  = (const float*)d_in[0];
    const void*  ei = d_in[1];
    const float* W1 = (const float*)d_in[2];
    const float* b1 = (const float*)d_in[3];
    const float* W2 = (const float*)d_in[4];
    const float* b2 = (const float*)d_in[5];
    const float* W3 = (const float*)d_in[6];
    const float* b3 = (const float*)d_in[7];
    float* out = (float*)d_out;

    char* ws = (char*)d_ws;
    size_t off = 0;
    auto alloc = [&](size_t bytes) { void* p = ws + off; off += (bytes + 255) & ~255ULL; return p; };
    int*   cursor  = (int*)alloc(NB * 4);
    int*   deg     = (int*)alloc(NN * 4);
    float* dis     = (float*)alloc(NN * 4);
    int*   offs    = (int*)alloc(NN * 4);
    int*   csr_tmp = (int*)alloc((size_t)NB * CAP * 4);   // 8 MB padded
    int*   csr     = (int*)alloc((size_t)NB * CAP * 4);   // 8 MB padded
    u16*   gbuf_s  = (u16*)alloc((size_t)NN * 64 * 2);    // slice-blocked [4][NN][16] bf16
    u16*   gbuf2_s = (u16*)alloc((size_t)NN * 64 * 2);    // slice-blocked [4][NN][16] bf16
    float* act_s   = (float*)alloc((size_t)NN * 64 * 4);  // slice-blocked [4][NN][16] fp32
    u16*   gbuf3   = (u16*)csr_tmp;  // alias: csr_tmp dead after k_sort; 8MB >= NN*40*2

    // CSR build: 2 kernels (padded-bucket counting sort, no global prefix)
    hipMemsetAsync(cursor, 0, NB * 4, stream);
    k_build<<<EB, 256, 0, stream>>>(ei, cursor, csr_tmp);
    k_sort<<<NB, 256, 0, stream>>>(cursor, csr_tmp, csr, deg, offs, dis);

    const int gemm_grid = (NN + GT_NODES - 1) / GT_NODES;   // 782
    const int slice_grid = (NN / 4) * 4;                    // 100,000 (4 slices)
    const int gather_grid = NN / 4;                         // 25,000

    // layer 1 GEMM: gbuf_s = bf16(dis * (x @ W1)), slice-blocked out
    k_gemm<128, 64, false, false, true><<<gemm_grid, 512, 0, stream>>>(x, W1, dis, gbuf_s);

    // layer 1 aggregation (sliced): act_s = dis*sum(gbuf_s) + b1
    k_gath16<<<slice_grid, 256, 0, stream>>>(offs, deg, csr, dis, gbuf_s, b1, act_s);

    // layer 2 GEMM: gbuf2_s = bf16(dis * (relu(act_s) @ W2)), sliced in+out
    k_gemm<64, 64, true, true, true><<<gemm_grid, 512, 0, stream>>>(act_s, W2, dis, gbuf2_s);

    // layer 2 aggregation (sliced): act_s = dis*sum(gbuf2_s) + b2
    k_gath16<<<slice_grid, 256, 0, stream>>>(offs, deg, csr, dis, gbuf2_s, b2, act_s);

    // layer 3 GEMM: gbuf3 = bf16(dis * (relu(act_s) @ W3)), node-major 40-wide out
    k_gemm<64, 40, true, true, false><<<gemm_grid, 512, 0, stream>>>(act_s, W3, dis, gbuf3);

    // final: out = log_softmax(dis*sum(gbuf3) + b3)  (proven node-major form)
    k_gather<40, true><<<gather_grid, 256, 0, stream>>>(offs, deg, csr, dis, gbuf3, b3, out);
}

// Round 8
// 328.303 us; speedup vs baseline: 1.4645x; 1.4645x over previous
//
#include <hip/hip_runtime.h>
#include <cstdint>
#include <cstddef>
#include <math.h>

#define NN 100000
#define NE 1600000
#define NB ((NN + 255) / 256)   // 391 node buckets (256 nodes each)
#define EB 400                  // build blocks
#define EPB (NE / EB)           // 4000 edges per block
#define CAP 5120                // padded bucket capacity (mean 4092, sigma~64)

// GEMM tiling: 512 threads, 128 nodes/block, per-thread 4 nodes x 4 feats.
#define GT_NODES 128
#define GT_KC 32
#define GT_STRIDE 132

typedef unsigned short u16;

__device__ __forceinline__ float bf2f(u16 u) {
    union { unsigned i; float f; } c; c.i = ((unsigned)u) << 16; return c.f;
}
__device__ __forceinline__ u16 f2bf(float f) {  // round-to-nearest-even
    union { float f; unsigned int i; } c; c.f = f;
    unsigned int lsb = (c.i >> 16) & 1u;
    return (u16)((c.i + 0x7fffu + lsb) >> 16);
}
__device__ __forceinline__ unsigned int pack2(float a, float b) {
    return (unsigned int)f2bf(a) | ((unsigned int)f2bf(b) << 16);
}

__device__ __forceinline__ int load_idx(const void* ei, int isI64, int pos) {
    if (isI64) return (int)((const long long*)ei)[pos];
    return ((const int*)ei)[pos];
}

// ---------- fused CSR phase A: detect + hist + scatter into padded buckets ----
__global__ __launch_bounds__(256) void k_build(const void* __restrict__ ei,
                                               int* __restrict__ cursor,
                                               int* __restrict__ csr_tmp) {
    __shared__ int sbuf[EPB];      // 16,000 B
    __shared__ int dbuf[EPB];      // 16,000 B
    __shared__ int cnt[NB];
    __shared__ int basel[NB];
    __shared__ int anynz;

    // per-block int64/int32 detection (odd words of first 1024 entries)
    const int* p = (const int*)ei;
    if (threadIdx.x == 0) anynz = 0;
    for (int i = threadIdx.x; i < NB; i += 256) cnt[i] = 0;
    __syncthreads();
    int nz = 0;
    for (int i = threadIdx.x; i < 1024; i += 256) nz |= (p[2 * i + 1] != 0);
    if (nz) anynz = 1;   // benign race: all writers store 1
    __syncthreads();
    int isI64 = (anynz == 0);

    int base = blockIdx.x * EPB;
    for (int i = threadIdx.x; i < EPB; i += 256) {
        int s = load_idx(ei, isI64, base + i);
        int d = load_idx(ei, isI64, NE + base + i);
        sbuf[i] = s;
        dbuf[i] = d;
        atomicAdd(&cnt[d >> 8], 1);
    }
    __syncthreads();
    for (int j = threadIdx.x; j < NB; j += 256) {
        int c = cnt[j];
        int g = c ? atomicAdd(&cursor[j], c) : 0;
        basel[j] = j * CAP + g;
        cnt[j] = 0;   // reuse as local placement cursor
    }
    __syncthreads();
    for (int i = threadIdx.x; i < EPB; i += 256) {
        int s = sbuf[i];
        int d = dbuf[i];
        int bkt = d >> 8;
        int slot = basel[bkt] + atomicAdd(&cnt[bkt], 1);
        csr_tmp[slot] = ((d & 255) << 17) | s;   // dstlocal<<17 | src
    }
}

// ---------- CSR phase B: per-bucket counting sort -> csr + deg/offs/dis ------
__global__ __launch_bounds__(256) void k_sort(const int* __restrict__ cursor,
                                              const int* __restrict__ csr_tmp,
                                              int* __restrict__ csr,
                                              int* __restrict__ deg,
                                              int* __restrict__ offs,
                                              float* __restrict__ dis) {
    __shared__ int h[256];
    __shared__ int sc[256];
    __shared__ int cur[256];
    int j = blockIdx.x;
    int s0 = j * CAP, s1 = s0 + cursor[j];
    h[threadIdx.x] = 0;
    __syncthreads();
    for (int p = s0 + threadIdx.x; p < s1; p += 256)
        atomicAdd(&h[csr_tmp[p] >> 17], 1);
    __syncthreads();
    int v = h[threadIdx.x];
    sc[threadIdx.x] = v;
    __syncthreads();
#pragma unroll
    for (int off = 1; off < 256; off <<= 1) {
        int u = (threadIdx.x >= off) ? sc[threadIdx.x - off] : 0;
        __syncthreads();
        sc[threadIdx.x] += u;
        __syncthreads();
    }
    int excl = sc[threadIdx.x] - v;
    int node = j * 256 + threadIdx.x;
    if (node < NN) {
        deg[node] = v;
        offs[node] = s0 + excl;
        dis[node] = rsqrtf((float)(v + 1));  // +1 self-loop
    }
    cur[threadIdx.x] = excl;
    __syncthreads();
    for (int p = s0 + threadIdx.x; p < s1; p += 256) {
        int pk = csr_tmp[p];
        int dl = pk >> 17;
        int pos = s0 + atomicAdd(&cur[dl], 1);
        csr[pos] = pk & 0x1FFFF;   // plain src index
    }
}

// ---------- register-tiled GEMM (512 thr, 128 nodes/blk, 4x4/thread) ----------
// R13 proven form. g[n][j] = bf16( dis[n] * (act(x)[n][:] @ W[:][j]) )
template <int K, int FR, bool RELU>
__global__ __launch_bounds__(512) void k_gemm(const float* __restrict__ x,
                                              const float* __restrict__ W,
                                              const float* __restrict__ dis,
                                              u16* __restrict__ out) {
    __shared__ float xT[GT_KC * GT_STRIDE];   // 16,896 B
    __shared__ float Wc[GT_KC * 64];          //  8,192 B
    const int tid = threadIdx.x;
    const int r = tid >> 4;
    const int c = tid & 15;
    const int f4 = tid & 7;
    const int nrow = tid >> 3;
    const int nbase = blockIdx.x * GT_NODES;

    float acc[4][4];
#pragma unroll
    for (int i = 0; i < 4; ++i)
#pragma unroll
        for (int j = 0; j < 4; ++j) acc[i][j] = 0.f;

    for (int kc = 0; kc < K; kc += GT_KC) {
#pragma unroll
        for (int q = 0; q < 4; ++q) {
            int e = q * 512 + tid;
            int kk = e >> 6, j = e & 63;
            Wc[kk * 64 + j] = (j < FR) ? W[(size_t)(kc + kk) * FR + j] : 0.f;
        }
#pragma unroll
        for (int q = 0; q < 2; ++q) {
            int nl = q * 64 + nrow;
            int n = nbase + nl;
            float4 v = make_float4(0.f, 0.f, 0.f, 0.f);
            if (n < NN) v = *(const float4*)(x + (size_t)n * K + kc + f4 * 4);
            if (RELU) {
                v.x = fmaxf(v.x, 0.f); v.y = fmaxf(v.y, 0.f);
                v.z = fmaxf(v.z, 0.f); v.w = fmaxf(v.w, 0.f);
            }
            xT[(f4 * 4 + 0) * GT_STRIDE + nl] = v.x;
            xT[(f4 * 4 + 1) * GT_STRIDE + nl] = v.y;
            xT[(f4 * 4 + 2) * GT_STRIDE + nl] = v.z;
            xT[(f4 * 4 + 3) * GT_STRIDE + nl] = v.w;
        }
        __syncthreads();
#pragma unroll 8
        for (int kk = 0; kk < GT_KC; ++kk) {
            float4 a = *(const float4*)&xT[kk * GT_STRIDE + r * 4];
            float4 w = *(const float4*)&Wc[kk * 64 + c * 4];
            float xa[4] = {a.x, a.y, a.z, a.w};
            float wb[4] = {w.x, w.y, w.z, w.w};
#pragma unroll
            for (int i = 0; i < 4; ++i)
#pragma unroll
                for (int j = 0; j < 4; ++j)
                    acc[i][j] = fmaf(xa[i], wb[j], acc[i][j]);
        }
        __syncthreads();
    }
    if (c * 4 < FR) {
#pragma unroll
        for (int i = 0; i < 4; ++i) {
            int n = nbase + r * 4 + i;
            if (n < NN) {
                float dv = dis[n];
                uint2 o;
                o.x = pack2(dv * acc[i][0], dv * acc[i][1]);
                o.y = pack2(dv * acc[i][2], dv * acc[i][3]);
                *(uint2*)(out + (size_t)n * FR + c * 4) = o;
            }
        }
    }
}

// ---------- R18 gather batch: B edges, dword (feat-pair) loads ----------
// Lane = (feat_pair fc2 = lane&31, edge-half eh = lane>>5). Each step loads
// ONE u32 (2 bf16 feats) for edge (i + 2k + eh): a quarter-wave (16 lanes x
// 4 B) covers exactly one 64-B line -> 2 requests/row instead of u16-form's
// 4 half-utilized 32-B quarter-requests. Same bytes, same instr count.
template <int F, int B, bool MASK>
__device__ __forceinline__ float2 gb2(int myidx, int i, int lim, int eh,
                                      const u16* __restrict__ g, unsigned fp) {
    unsigned off[B / 2];
#pragma unroll
    for (int k = 0; k < B / 2; ++k) {
        int s = __shfl(myidx, i + 2 * k + eh);
        off[k] = (unsigned)s * (unsigned)(F * 2) + fp * 4u;
    }
    unsigned hv[B / 2];
#pragma unroll
    for (int k = 0; k < B / 2; ++k)
        hv[k] = *(const unsigned*)((const char*)g + off[k]);
    float x0 = 0.f, x1 = 0.f, y0 = 0.f, y1 = 0.f;
#pragma unroll
    for (int k = 0; k < B / 2; ++k) {
        float vx = bf2f((u16)(hv[k] & 0xffffu));
        float vy = bf2f((u16)(hv[k] >> 16));
        if (MASK) {
            bool ok = (i + 2 * k + eh) < lim;
            vx = ok ? vx : 0.f;
            vy = ok ? vy : 0.f;
        }
        if (k & 1) { x1 += vx; y1 += vy; }
        else       { x0 += vx; y0 += vy; }
    }
    float2 r; r.x = x0 + x1; r.y = y0 + y1; return r;
}

// ---------- R18 gather: out[n][f] = dis[n]*(g[n][f] + sum_e g[src_e][f]) + b[f]
// Node per wave (R14 lesson: keep 100K wave streams). Indices staged once
// across lanes; per-edge delivery via __shfl. Batch widths 16/32 chosen by
// degree (R13 proven). Cross-half reduce: one __shfl_xor(32) pair.
template <int F, bool SOFTMAX>
__global__ __launch_bounds__(256) void k_gather2(const int* __restrict__ offs,
                                                 const int* __restrict__ deg,
                                                 const int* __restrict__ csr,
                                                 const float* __restrict__ dis,
                                                 const u16* __restrict__ g,
                                                 const float* __restrict__ b,
                                                 float* __restrict__ out) {
    int n = blockIdx.x * 4 + (threadIdx.x >> 6);   // grid exact: n < NN
    unsigned lane = threadIdx.x & 63;
    unsigned fc2 = lane & 31;                      // feature-pair id
    int eh = (int)(lane >> 5);                     // edge-half 0/1
    bool valid = (2u * fc2 < (unsigned)F);
    unsigned fp = valid ? fc2 : (unsigned)(F / 2 - 1);

    int start = __builtin_amdgcn_readfirstlane(offs[n]);
    int len   = __builtin_amdgcn_readfirstlane(deg[n]);
    float dvn = dis[n];

    // self-loop row (pre-scaled by dis[n]); count once (eh==0 half only)
    unsigned sv = *(const unsigned*)((const char*)g
                      + (size_t)(unsigned)n * (unsigned)(F * 2) + fp * 4u);
    float2 acc;
    acc.x = eh ? 0.f : bf2f((u16)(sv & 0xffffu));
    acc.y = eh ? 0.f : bf2f((u16)(sv >> 16));

    int myidx = 0;
    if ((int)lane < len) myidx = csr[start + (int)lane];
    int lim = (len < 64) ? len : 64;

    if (lim > 0) {
        float2 t;
        if (lim >= 33) {
            int i = 0;
            for (; i + 16 <= lim; i += 16) {
                t = gb2<F, 16, false>(myidx, i, lim, eh, g, fp);
                acc.x += t.x; acc.y += t.y;
            }
            if (i < lim) {
                t = gb2<F, 16, true>(myidx, i, lim, eh, g, fp);
                acc.x += t.x; acc.y += t.y;
            }
        } else if (lim >= 17) {
            t = gb2<F, 32, true>(myidx, 0, lim, eh, g, fp);
            acc.x += t.x; acc.y += t.y;
        } else if (lim == 16) {
            t = gb2<F, 16, false>(myidx, 0, lim, eh, g, fp);
            acc.x += t.x; acc.y += t.y;
        } else {
            t = gb2<F, 16, true>(myidx, 0, lim, eh, g, fp);
            acc.x += t.x; acc.y += t.y;
        }
    }
    // rare fallback: deg > 64 (halves take alternate edges)
    if (len > 64) {
        for (int i = 64 + eh; i < len; i += 2) {
            int s = csr[start + i];
            unsigned hv = *(const unsigned*)((const char*)g
                              + (unsigned)s * (unsigned)(F * 2) + fp * 4u);
            acc.x += bf2f((u16)(hv & 0xffffu));
            acc.y += bf2f((u16)(hv >> 16));
        }
    }
    // combine the two edge-halves
    acc.x += __shfl_xor(acc.x, 32);
    acc.y += __shfl_xor(acc.y, 32);

    float vx = dvn * acc.x + b[2 * fp + 0];
    float vy = dvn * acc.y + b[2 * fp + 1];

    if (!SOFTMAX) {
        if (eh == 0 && valid) {
            float2 o; o.x = vx; o.y = vy;
            *(float2*)(out + (size_t)n * F + 2 * fp) = o;
        }
    } else {
        float m = valid ? fmaxf(vx, vy) : -INFINITY;
#pragma unroll
        for (int off = 16; off; off >>= 1) m = fmaxf(m, __shfl_xor(m, off));
        float ex = valid ? (__expf(vx - m) + __expf(vy - m)) : 0.f;
        float sum = ex;
#pragma unroll
        for (int off = 16; off; off >>= 1) sum += __shfl_xor(sum, off);
        if (eh == 0 && valid) {
            float ls = logf(sum);
            float2 o; o.x = vx - m - ls; o.y = vy - m - ls;
            *(float2*)(out + (size_t)n * F + 2 * fp) = o;
        }
    }
}

extern "C" void kernel_launch(void* const* d_in, const int* in_sizes, int n_in,
                              void* d_out, int out_size, void* d_ws, size_t ws_size,
                              hipStream_t stream) {
    const float* x  = (const float*)d_in[0];
    const void*  ei = d_in[1];
    const float* W1 = (const float*)d_in[2];
    const float* b1 = (const float*)d_in[3];
    const float* W2 = (const float*)d_in[4];
    const float* b2 = (const float*)d_in[5];
    const float* W3 = (const float*)d_in[6];
    const float* b3 = (const float*)d_in[7];
    float* out = (float*)d_out;

    char* ws = (char*)d_ws;
    size_t off = 0;
    auto alloc = [&](size_t bytes) { void* p = ws + off; off += (bytes + 255) & ~255ULL; return p; };
    int*   cursor  = (int*)alloc(NB * 4);
    int*   deg     = (int*)alloc(NN * 4);
    float* dis     = (float*)alloc(NN * 4);
    int*   offs    = (int*)alloc(NN * 4);
    int*   csr_tmp = (int*)alloc((size_t)NB * CAP * 4);   // 8 MB padded
    int*   csr     = (int*)alloc((size_t)NB * CAP * 4);   // 8 MB padded
    u16*   gbuf    = (u16*)alloc((size_t)NN * 64 * 2);    // bf16 staging (12.8 MB)
    float* act     = (float*)alloc((size_t)NN * 64 * 4);  // fp32 inter-layer activations

    // CSR build: 2 kernels (padded-bucket counting sort, no global prefix)
    hipMemsetAsync(cursor, 0, NB * 4, stream);
    k_build<<<EB, 256, 0, stream>>>(ei, cursor, csr_tmp);
    k_sort<<<NB, 256, 0, stream>>>(cursor, csr_tmp, csr, deg, offs, dis);

    const int gemm_grid = (NN + GT_NODES - 1) / GT_NODES;   // 782
    const int gather_grid = NN / 4;                         // 25000 (exact)

    // layer 1: g1 = bf16(dis*(x@W1)); act = dis*(sum g1) + b1 (ReLU in next gemm)
    k_gemm<128, 64, false><<<gemm_grid, 512, 0, stream>>>(x, W1, dis, gbuf);
    k_gather2<64, false><<<gather_grid, 256, 0, stream>>>(offs, deg, csr, dis, gbuf, b1, act);

    // layer 2
    k_gemm<64, 64, true><<<gemm_grid, 512, 0, stream>>>(act, W2, dis, gbuf);
    k_gather2<64, false><<<gather_grid, 256, 0, stream>>>(offs, deg, csr, dis, gbuf, b2, act);

    // layer 3 + fused log_softmax (tight 40-wide staging rows)
    k_gemm<64, 40, true><<<gemm_grid, 512, 0, stream>>>(act, W3, dis, gbuf);
    k_gather2<40, true><<<gather_grid, 256, 0, stream>>>(offs, deg, csr, dis, gbuf, b3, out);
}

// Round 9
// 287.622 us; speedup vs baseline: 1.6716x; 1.1414x over previous
//
#include <hip/hip_runtime.h>
#include <cstdint>
#include <cstddef>
#include <math.h>

#define NN 100000
#define NE 1600000
#define NB ((NN + 255) / 256)   // 391 node buckets (256 nodes each)
#define EB 400                  // build blocks
#define EPB (NE / EB)           // 4000 edges per block
#define CAP 5120                // padded bucket capacity (mean 4092, sigma~64)

#define MS 40                   // MFMA LDS row stride in u16 (80 B: 16-B aligned frags, 2-way banks)

typedef unsigned short u16;
typedef __attribute__((ext_vector_type(8))) short bf16x8;
typedef __attribute__((ext_vector_type(4))) float f32x4;

__device__ __forceinline__ float bf2f(u16 u) {
    union { unsigned i; float f; } c; c.i = ((unsigned)u) << 16; return c.f;
}
__device__ __forceinline__ u16 f2bf(float f) {  // round-to-nearest-even
    union { float f; unsigned int i; } c; c.f = f;
    unsigned int lsb = (c.i >> 16) & 1u;
    return (u16)((c.i + 0x7fffu + lsb) >> 16);
}

__device__ __forceinline__ int load_idx(const void* ei, int isI64, int pos) {
    if (isI64) return (int)((const long long*)ei)[pos];
    return ((const int*)ei)[pos];
}

// ---------- fused CSR phase A: detect + hist + scatter into padded buckets ----
__global__ __launch_bounds__(256) void k_build(const void* __restrict__ ei,
                                               int* __restrict__ cursor,
                                               int* __restrict__ csr_tmp) {
    __shared__ int sbuf[EPB];      // 16,000 B
    __shared__ int dbuf[EPB];      // 16,000 B
    __shared__ int cnt[NB];
    __shared__ int basel[NB];
    __shared__ int anynz;

    const int* p = (const int*)ei;
    if (threadIdx.x == 0) anynz = 0;
    for (int i = threadIdx.x; i < NB; i += 256) cnt[i] = 0;
    __syncthreads();
    int nz = 0;
    for (int i = threadIdx.x; i < 1024; i += 256) nz |= (p[2 * i + 1] != 0);
    if (nz) anynz = 1;   // benign race: all writers store 1
    __syncthreads();
    int isI64 = (anynz == 0);

    int base = blockIdx.x * EPB;
    for (int i = threadIdx.x; i < EPB; i += 256) {
        int s = load_idx(ei, isI64, base + i);
        int d = load_idx(ei, isI64, NE + base + i);
        sbuf[i] = s;
        dbuf[i] = d;
        atomicAdd(&cnt[d >> 8], 1);
    }
    __syncthreads();
    for (int j = threadIdx.x; j < NB; j += 256) {
        int c = cnt[j];
        int g = c ? atomicAdd(&cursor[j], c) : 0;
        basel[j] = j * CAP + g;
        cnt[j] = 0;   // reuse as local placement cursor
    }
    __syncthreads();
    for (int i = threadIdx.x; i < EPB; i += 256) {
        int s = sbuf[i];
        int d = dbuf[i];
        int bkt = d >> 8;
        int slot = basel[bkt] + atomicAdd(&cnt[bkt], 1);
        csr_tmp[slot] = ((d & 255) << 17) | s;   // dstlocal<<17 | src
    }
}

// ---------- CSR phase B: per-bucket counting sort -> csr + deg/offs/dis ------
__global__ __launch_bounds__(256) void k_sort(const int* __restrict__ cursor,
                                              const int* __restrict__ csr_tmp,
                                              int* __restrict__ csr,
                                              int* __restrict__ deg,
                                              int* __restrict__ offs,
                                              float* __restrict__ dis) {
    __shared__ int h[256];
    __shared__ int sc[256];
    __shared__ int cur[256];
    int j = blockIdx.x;
    int s0 = j * CAP, s1 = s0 + cursor[j];
    h[threadIdx.x] = 0;
    __syncthreads();
    for (int p = s0 + threadIdx.x; p < s1; p += 256)
        atomicAdd(&h[csr_tmp[p] >> 17], 1);
    __syncthreads();
    int v = h[threadIdx.x];
    sc[threadIdx.x] = v;
    __syncthreads();
#pragma unroll
    for (int off = 1; off < 256; off <<= 1) {
        int u = (threadIdx.x >= off) ? sc[threadIdx.x - off] : 0;
        __syncthreads();
        sc[threadIdx.x] += u;
        __syncthreads();
    }
    int excl = sc[threadIdx.x] - v;
    int node = j * 256 + threadIdx.x;
    if (node < NN) {
        deg[node] = v;
        offs[node] = s0 + excl;
        dis[node] = rsqrtf((float)(v + 1));  // +1 self-loop
    }
    cur[threadIdx.x] = excl;
    __syncthreads();
    for (int p = s0 + threadIdx.x; p < s1; p += 256) {
        int pk = csr_tmp[p];
        int dl = pk >> 17;
        int pos = s0 + atomicAdd(&cur[dl], 1);
        csr[pos] = pk & 0x1FFFF;   // plain src index
    }
}

// ---------- R19: MFMA GEMM (512 thr = 8 waves, 128 nodes/block) ----------
// g[n][j] = bf16( dis[n] * (act(x)[n][:] @ W[:][j]) ), via
// mfma_f32_16x16x32_bf16. Precision: x split hi+lo bf16 (2 MFMAs) so only
// W's 2^-9 rounding adds error (~15x below existing staging error).
// Layouts (m89/m91-verified C/D; standard A/B):
//   A: row=lane&15, k=(lane>>4)*8+j   B: col=lane&15, k=(lane>>4)*8+j
//   D: col=lane&15, row=(lane>>4)*4+reg
// LDS stride MS=40 u16 (80 B): frag b128 reads 16-B aligned, banks 2-way (free).
template <int K, int FR, bool RELU>
__global__ __launch_bounds__(512) void k_gemm_m(const float* __restrict__ x,
                                                const float* __restrict__ W,
                                                const float* __restrict__ dis,
                                                u16* __restrict__ out) {
    __shared__ u16 Ah[128 * MS];   // 10,240 B  x-hi bf16
    __shared__ u16 Al[128 * MS];   // 10,240 B  x-lo bf16
    __shared__ u16 Bw[64 * MS];    //  5,120 B  W^T bf16 [col][k]
    const int tid = threadIdx.x;
    const int w = tid >> 6;        // wave 0..7 -> M-strip rows w*16..+16
    const int l = tid & 63;
    const int row16 = l & 15;
    const int kg = l >> 4;
    const int nbase = blockIdx.x * 128;

    f32x4 acc[4];
#pragma unroll
    for (int t = 0; t < 4; ++t) acc[t] = (f32x4){0.f, 0.f, 0.f, 0.f};

    for (int kc = 0; kc < K; kc += 32) {
        // ---- stage x (fp32 -> hi/lo bf16), 8 floats/thread ----
        {
            int r = tid >> 2;          // 0..127
            int cg = tid & 3;          // 8-float group
            int n = nbase + r;
            float vs[8];
#pragma unroll
            for (int j = 0; j < 8; ++j) vs[j] = 0.f;
            if (n < NN) {
                const float* xp = x + (size_t)n * K + kc + cg * 8;
                float4 v0 = *(const float4*)xp;
                float4 v1 = *(const float4*)(xp + 4);
                vs[0] = v0.x; vs[1] = v0.y; vs[2] = v0.z; vs[3] = v0.w;
                vs[4] = v1.x; vs[5] = v1.y; vs[6] = v1.z; vs[7] = v1.w;
            }
            if (RELU) {
#pragma unroll
                for (int j = 0; j < 8; ++j) vs[j] = fmaxf(vs[j], 0.f);
            }
            u16* ah = &Ah[r * MS + cg * 8];
            u16* al = &Al[r * MS + cg * 8];
#pragma unroll
            for (int j = 0; j < 8; j += 2) {
                u16 h0 = f2bf(vs[j]);
                u16 h1 = f2bf(vs[j + 1]);
                float r0 = vs[j] - bf2f(h0);
                float r1 = vs[j + 1] - bf2f(h1);
                *(unsigned*)&ah[j] = (unsigned)h0 | ((unsigned)h1 << 16);
                *(unsigned*)&al[j] = (unsigned)f2bf(r0) | ((unsigned)f2bf(r1) << 16);
            }
        }
        // ---- stage W transposed: Bw[col][k], zero-pad cols >= FR ----
        {
            int k = tid >> 4;          // 0..31
            int c0 = (tid & 15) * 4;   // 0..60
#pragma unroll
            for (int j = 0; j < 4; ++j) {
                int c = c0 + j;
                float wv = (c < FR) ? W[(size_t)(kc + k) * FR + c] : 0.f;
                Bw[c * MS + k] = f2bf(wv);
            }
        }
        __syncthreads();
        // ---- fragments + MFMA ----
        bf16x8 ah = *(const bf16x8*)&Ah[(w * 16 + row16) * MS + kg * 8];
        bf16x8 al = *(const bf16x8*)&Al[(w * 16 + row16) * MS + kg * 8];
#pragma unroll
        for (int t = 0; t < 4; ++t) {
            bf16x8 b = *(const bf16x8*)&Bw[(t * 16 + row16) * MS + kg * 8];
            acc[t] = __builtin_amdgcn_mfma_f32_16x16x32_bf16(ah, b, acc[t], 0, 0, 0);
            acc[t] = __builtin_amdgcn_mfma_f32_16x16x32_bf16(al, b, acc[t], 0, 0, 0);
        }
        __syncthreads();
    }
    // ---- epilogue: D[row=(kg*4+r)][col=row16] -> out[n][feat] ----
#pragma unroll
    for (int r = 0; r < 4; ++r) {
        int n = nbase + w * 16 + kg * 4 + r;
        if (n < NN) {
            float dv = dis[n];
#pragma unroll
            for (int t = 0; t < 4; ++t) {
                int feat = t * 16 + row16;
                if (feat < FR)
                    out[(size_t)n * FR + feat] = f2bf(dv * acc[t][r]);
            }
        }
    }
}

// ---------- R18 gather batch: B edges, dword (feat-pair) loads ----------
// Lane = (feat_pair fc2 = lane&31, edge-half eh = lane>>5). Quarter-wave
// (16 lanes x 4 B) covers exactly one 64-B line -> 2 requests/row (proven
// -10% vs u16 form, R18 measured 48->43.3 us).
template <int F, int B, bool MASK>
__device__ __forceinline__ float2 gb2(int myidx, int i, int lim, int eh,
                                      const u16* __restrict__ g, unsigned fp) {
    unsigned off[B / 2];
#pragma unroll
    for (int k = 0; k < B / 2; ++k) {
        int s = __shfl(myidx, i + 2 * k + eh);
        off[k] = (unsigned)s * (unsigned)(F * 2) + fp * 4u;
    }
    unsigned hv[B / 2];
#pragma unroll
    for (int k = 0; k < B / 2; ++k)
        hv[k] = *(const unsigned*)((const char*)g + off[k]);
    float x0 = 0.f, x1 = 0.f, y0 = 0.f, y1 = 0.f;
#pragma unroll
    for (int k = 0; k < B / 2; ++k) {
        float vx = bf2f((u16)(hv[k] & 0xffffu));
        float vy = bf2f((u16)(hv[k] >> 16));
        if (MASK) {
            bool ok = (i + 2 * k + eh) < lim;
            vx = ok ? vx : 0.f;
            vy = ok ? vy : 0.f;
        }
        if (k & 1) { x1 += vx; y1 += vy; }
        else       { x0 += vx; y0 += vy; }
    }
    float2 r; r.x = x0 + x1; r.y = y0 + y1; return r;
}

// ---------- R18 gather: out[n][f] = dis[n]*(g[n][f] + sum_e g[src_e][f]) + b[f]
template <int F, bool SOFTMAX>
__global__ __launch_bounds__(256) void k_gather2(const int* __restrict__ offs,
                                                 const int* __restrict__ deg,
                                                 const int* __restrict__ csr,
                                                 const float* __restrict__ dis,
                                                 const u16* __restrict__ g,
                                                 const float* __restrict__ b,
                                                 float* __restrict__ out) {
    int n = blockIdx.x * 4 + (threadIdx.x >> 6);   // grid exact: n < NN
    unsigned lane = threadIdx.x & 63;
    unsigned fc2 = lane & 31;                      // feature-pair id
    int eh = (int)(lane >> 5);                     // edge-half 0/1
    bool valid = (2u * fc2 < (unsigned)F);
    unsigned fp = valid ? fc2 : (unsigned)(F / 2 - 1);

    int start = __builtin_amdgcn_readfirstlane(offs[n]);
    int len   = __builtin_amdgcn_readfirstlane(deg[n]);
    float dvn = dis[n];

    unsigned sv = *(const unsigned*)((const char*)g
                      + (size_t)(unsigned)n * (unsigned)(F * 2) + fp * 4u);
    float2 acc;
    acc.x = eh ? 0.f : bf2f((u16)(sv & 0xffffu));
    acc.y = eh ? 0.f : bf2f((u16)(sv >> 16));

    int myidx = 0;
    if ((int)lane < len) myidx = csr[start + (int)lane];
    int lim = (len < 64) ? len : 64;

    if (lim > 0) {
        float2 t;
        if (lim >= 33) {
            int i = 0;
            for (; i + 16 <= lim; i += 16) {
                t = gb2<F, 16, false>(myidx, i, lim, eh, g, fp);
                acc.x += t.x; acc.y += t.y;
            }
            if (i < lim) {
                t = gb2<F, 16, true>(myidx, i, lim, eh, g, fp);
                acc.x += t.x; acc.y += t.y;
            }
        } else if (lim >= 17) {
            t = gb2<F, 32, true>(myidx, 0, lim, eh, g, fp);
            acc.x += t.x; acc.y += t.y;
        } else if (lim == 16) {
            t = gb2<F, 16, false>(myidx, 0, lim, eh, g, fp);
            acc.x += t.x; acc.y += t.y;
        } else {
            t = gb2<F, 16, true>(myidx, 0, lim, eh, g, fp);
            acc.x += t.x; acc.y += t.y;
        }
    }
    if (len > 64) {
        for (int i = 64 + eh; i < len; i += 2) {
            int s = csr[start + i];
            unsigned hv = *(const unsigned*)((const char*)g
                              + (unsigned)s * (unsigned)(F * 2) + fp * 4u);
            acc.x += bf2f((u16)(hv & 0xffffu));
            acc.y += bf2f((u16)(hv >> 16));
        }
    }
    acc.x += __shfl_xor(acc.x, 32);
    acc.y += __shfl_xor(acc.y, 32);

    float vx = dvn * acc.x + b[2 * fp + 0];
    float vy = dvn * acc.y + b[2 * fp + 1];

    if (!SOFTMAX) {
        if (eh == 0 && valid) {
            float2 o; o.x = vx; o.y = vy;
            *(float2*)(out + (size_t)n * F + 2 * fp) = o;
        }
    } else {
        float m = valid ? fmaxf(vx, vy) : -INFINITY;
#pragma unroll
        for (int off = 16; off; off >>= 1) m = fmaxf(m, __shfl_xor(m, off));
        float ex = valid ? (__expf(vx - m) + __expf(vy - m)) : 0.f;
        float sum = ex;
#pragma unroll
        for (int off = 16; off; off >>= 1) sum += __shfl_xor(sum, off);
        if (eh == 0 && valid) {
            float ls = logf(sum);
            float2 o; o.x = vx - m - ls; o.y = vy - m - ls;
            *(float2*)(out + (size_t)n * F + 2 * fp) = o;
        }
    }
}

extern "C" void kernel_launch(void* const* d_in, const int* in_sizes, int n_in,
                              void* d_out, int out_size, void* d_ws, size_t ws_size,
                              hipStream_t stream) {
    const float* x  = (const float*)d_in[0];
    const void*  ei = d_in[1];
    const float* W1 = (const float*)d_in[2];
    const float* b1 = (const float*)d_in[3];
    const float* W2 = (const float*)d_in[4];
    const float* b2 = (const float*)d_in[5];
    const float* W3 = (const float*)d_in[6];
    const float* b3 = (const float*)d_in[7];
    float* out = (float*)d_out;

    char* ws = (char*)d_ws;
    size_t off = 0;
    auto alloc = [&](size_t bytes) { void* p = ws + off; off += (bytes + 255) & ~255ULL; return p; };
    int*   cursor  = (int*)alloc(NB * 4);
    int*   deg     = (int*)alloc(NN * 4);
    float* dis     = (float*)alloc(NN * 4);
    int*   offs    = (int*)alloc(NN * 4);
    int*   csr_tmp = (int*)alloc((size_t)NB * CAP * 4);   // 8 MB padded
    int*   csr     = (int*)alloc((size_t)NB * CAP * 4);   // 8 MB padded
    u16*   gbuf    = (u16*)alloc((size_t)NN * 64 * 2);    // bf16 staging (12.8 MB)
    float* act     = (float*)alloc((size_t)NN * 64 * 4);  // fp32 inter-layer activations

    // CSR build: 2 kernels (padded-bucket counting sort, no global prefix)
    hipMemsetAsync(cursor, 0, NB * 4, stream);
    k_build<<<EB, 256, 0, stream>>>(ei, cursor, csr_tmp);
    k_sort<<<NB, 256, 0, stream>>>(cursor, csr_tmp, csr, deg, offs, dis);

    const int gemm_grid = (NN + 127) / 128;   // 782
    const int gather_grid = NN / 4;           // 25000 (exact)

    // layer 1: g1 = bf16(dis*(x@W1)); act = dis*(sum g1) + b1 (ReLU in next gemm)
    k_gemm_m<128, 64, false><<<gemm_grid, 512, 0, stream>>>(x, W1, dis, gbuf);
    k_gather2<64, false><<<gather_grid, 256, 0, stream>>>(offs, deg, csr, dis, gbuf, b1, act);

    // layer 2
    k_gemm_m<64, 64, true><<<gemm_grid, 512, 0, stream>>>(act, W2, dis, gbuf);
    k_gather2<64, false><<<gather_grid, 256, 0, stream>>>(offs, deg, csr, dis, gbuf, b2, act);

    // layer 3 + fused log_softmax (tight 40-wide staging rows)
    k_gemm_m<64, 40, true><<<gemm_grid, 512, 0, stream>>>(act, W3, dis, gbuf);
    k_gather2<40, true><<<gather_grid, 256, 0, stream>>>(offs, deg, csr, dis, gbuf, b3, out);
}